// Round 6
// baseline (110.719 us; speedup 1.0000x reference)
//
#include <hip/hip_runtime.h>
#include <hip/hip_bf16.h>

#define NN 8192
#define KK 256
#define HN 4096
#define TM 256
#define TN 128
#define NBLK 1056  // lower-triangle 256x128 tiles: 8*132, bijective XCD swizzle

typedef __attribute__((ext_vector_type(8))) short bf16x8;
typedef __attribute__((ext_vector_type(4))) float f32x4;

// ---- Kernel 1: row-normalize z (f32) -> zn (bf16); block 0 zeroes out ----
__global__ void nrm_kernel(const float* __restrict__ z,
                           unsigned short* __restrict__ zn,
                           float* __restrict__ out) {
  if (blockIdx.x == 0 && threadIdx.x == 0) out[0] = 0.0f;
  int row = (blockIdx.x << 2) + (threadIdx.x >> 6);
  int lane = threadIdx.x & 63;
  float4 v = ((const float4*)(z + (size_t)row * KK))[lane];
  float ss = v.x * v.x + v.y * v.y + v.z * v.z + v.w * v.w;
#pragma unroll
  for (int off = 32; off; off >>= 1) ss += __shfl_xor(ss, off, 64);
  float scale = 1.0f / fmaxf(sqrtf(ss), 1e-8f);
  union {
    __hip_bfloat16 h[4];
    ushort4 u;
  } cv;
  cv.h[0] = __float2bfloat16(v.x * scale);
  cv.h[1] = __float2bfloat16(v.y * scale);
  cv.h[2] = __float2bfloat16(v.z * scale);
  cv.h[3] = __float2bfloat16(v.w * scale);
  ((ushort4*)zn)[(size_t)row * 64 + lane] = cv.u;
}

// ---- Kernel 2: symmetric Gram-GEMM, 256x128 lower-triangle tiles ----
// NO LDS, NO barriers: MFMA fragments are loaded directly from global
// (zn is 4 MB = per-XCD-L2-resident; a fragment load's 64 lanes cover
// 16 rows x 64 contiguous bytes = 16 full cache lines, fully coalesced).
// p = exp(10*s_ij-10) for j<i credited to row i and col j partial sums in
// per-wave-private slots: rowpartT[2bn+wc][row], colpartT[2bm+wr][col].
__global__ __launch_bounds__(256, 2) void gemm_kernel(
    const unsigned short* __restrict__ zn, float* __restrict__ rowpartT,
    float* __restrict__ colpartT, float* __restrict__ pos) {
  const int t = threadIdx.x;
  // XCD-aware bijective swizzle (1056 = 8*132), then lower-tri decode
  int id = ((int)blockIdx.x & 7) * 132 + ((int)blockIdx.x >> 3);
  int bm = (int)((sqrtf((float)(4 * id + 1)) - 1.0f) * 0.5f);
  while (bm * (bm + 1) > id) --bm;
  while ((bm + 1) * (bm + 2) <= id) ++bm;
  const int bn = id - bm * (bm + 1);  // 0 .. 2*bm+1

  const int l = t & 63;
  const int w = t >> 6;   // 0..3
  const int wr = w >> 1;  // 0..1 : 128-row half
  const int wc = w & 1;   // 0..1 : 64-col half

  f32x4 acc[8][4];
  const f32x4 vzero = {0.f, 0.f, 0.f, 0.f};
#pragma unroll
  for (int mi = 0; mi < 8; ++mi)
#pragma unroll
    for (int ni = 0; ni < 4; ++ni) acc[mi][ni] = vzero;

  const char* zb = (const char*)zn;
  // fragment base addresses: row = base + (l&15), 16B at k-offset (l>>4)*16
  const char* aBase =
      zb + (size_t)(bm * TM + wr * 128 + (l & 15)) * 512 + ((l >> 4) << 4);
  const char* bBase =
      zb + (size_t)(bn * TN + wc * 64 + (l & 15)) * 512 + ((l >> 4) << 4);

#pragma unroll
  for (int kc = 0; kc < KK / 32; ++kc) {  // 8 chunks of k=32
    bf16x8 af[8], bf[4];
#pragma unroll
    for (int mi = 0; mi < 8; ++mi)
      af[mi] = *(const bf16x8*)(aBase + mi * (16 * 512) + kc * 64);
#pragma unroll
    for (int ni = 0; ni < 4; ++ni)
      bf[ni] = *(const bf16x8*)(bBase + ni * (16 * 512) + kc * 64);
#pragma unroll
    for (int mi = 0; mi < 8; ++mi)
#pragma unroll
      for (int ni = 0; ni < 4; ++ni)
        acc[mi][ni] = __builtin_amdgcn_mfma_f32_16x16x32_bf16(
            af[mi], bf[ni], acc[mi][ni], 0, 0, 0);
  }

  // ---- epilogue: p = exp(10s-10) for gc<gr only; private partial slots ----
  const int g16 = l >> 4;
  const int rowBase = bm * TM + wr * 128 + (g16 << 2);
  const int colBase = bn * TN + wc * 64 + (l & 15);
  const float C1 = 14.4269504088896340736f;  // 10*log2(e)
  float rs[8][4];
  float cs[4] = {0.f, 0.f, 0.f, 0.f};
#pragma unroll
  for (int mi = 0; mi < 8; ++mi) {
#pragma unroll
    for (int j = 0; j < 4; ++j) rs[mi][j] = 0.f;
#pragma unroll
    for (int ni = 0; ni < 4; ++ni) {
#pragma unroll
      for (int j = 0; j < 4; ++j) {
        int gr = rowBase + mi * 16 + j;
        int gc = colBase + ni * 16;
        float a = acc[mi][ni][j];
        if (gc == (gr ^ HN)) {  // strictly-lower hit: write both directions
          pos[gr] = a * 10.0f;
          pos[gc] = a * 10.0f;
        }
        float p = (gc < gr) ? exp2f(fmaf(a, C1, -C1)) : 0.0f;
        rs[mi][j] += p;
        cs[ni] += p;
      }
    }
  }
  // reduce rs across the 16 col-lanes; cs across the 4 row-lane groups
#pragma unroll
  for (int mi = 0; mi < 8; ++mi)
#pragma unroll
    for (int j = 0; j < 4; ++j) {
      float v = rs[mi][j];
      v += __shfl_xor(v, 1, 64);
      v += __shfl_xor(v, 2, 64);
      v += __shfl_xor(v, 4, 64);
      v += __shfl_xor(v, 8, 64);
      rs[mi][j] = v;  // valid in lanes with (l&15)==0
    }
#pragma unroll
  for (int ni = 0; ni < 4; ++ni) {
    float v = cs[ni];
    v += __shfl_xor(v, 16, 64);
    v += __shfl_xor(v, 32, 64);
    cs[ni] = v;  // valid in lanes l<16
  }
  // private-slot stores: one writer per slot element, no merge needed
  if ((l & 15) == 0) {
    float* dst = rowpartT + (size_t)(2 * bn + wc) * NN;
#pragma unroll
    for (int mi = 0; mi < 8; ++mi) {
      float4 v4 = make_float4(rs[mi][0], rs[mi][1], rs[mi][2], rs[mi][3]);
      *(float4*)(dst + rowBase + mi * 16) = v4;
    }
  }
  if (l < 16) {
    float* dst = colpartT + (size_t)(2 * bm + wr) * NN;
#pragma unroll
    for (int ni = 0; ni < 4; ++ni) dst[colBase + ni * 16] = cs[ni];
  }
}

// ---- Kernel 3: loss = mean(10 + ln(rowsum_i) - pos_i) ----
__global__ void finalize_kernel(const float* __restrict__ rowpartT,
                                const float* __restrict__ colpartT,
                                const float* __restrict__ pos,
                                float* __restrict__ out) {
  int i = blockIdx.x * 256 + threadIdx.x;  // one row per thread
  int bm = i >> 8, cn = i >> 7;
  float sum = 0.f;
  // row slots: 2bn+wc for bn=0..2bm+1 -> k in [0, 4bm+4)
  for (int k = 0; k < 4 * bm + 4; ++k) sum += rowpartT[(size_t)k * NN + i];
  // col slots: 2s+wr for s=(cn>>1)..31 -> k in [cn&~1, 64)
  for (int k = (cn & ~1); k < 64; ++k) sum += colpartT[(size_t)k * NN + i];
  float acc = 10.0f + logf(sum) - pos[i];
#pragma unroll
  for (int off = 32; off; off >>= 1) acc += __shfl_xor(acc, off, 64);
  __shared__ float ws[4];
  if ((threadIdx.x & 63) == 0) ws[threadIdx.x >> 6] = acc;
  __syncthreads();
  if (threadIdx.x == 0)
    atomicAdd(out, (ws[0] + ws[1] + ws[2] + ws[3]) * (1.0f / (float)NN));
}

extern "C" void kernel_launch(void* const* d_in, const int* in_sizes, int n_in,
                              void* d_out, int out_size, void* d_ws,
                              size_t ws_size, hipStream_t stream) {
  const float* z = (const float*)d_in[0];
  float* out = (float*)d_out;
  char* ws = (char*)d_ws;
  unsigned short* zn = (unsigned short*)ws;     // 4 MiB bf16
  float* rowpartT = (float*)(ws + (4 << 20));   // 4 MiB [128][8192]
  float* colpartT = (float*)(ws + (8 << 20));   // 2 MiB [64][8192]
  float* pos = (float*)(ws + (10 << 20));       // 32 KiB

  nrm_kernel<<<NN / 4, 256, 0, stream>>>(z, zn, out);
  gemm_kernel<<<NBLK, 256, 0, stream>>>(zn, rowpartT, colpartT, pos);
  finalize_kernel<<<NN / 256, 256, 0, stream>>>(rowpartT, colpartT, pos, out);
}

// Round 7
// 81.288 us; speedup vs baseline: 1.3621x; 1.3621x over previous
//
#include <hip/hip_runtime.h>
#include <hip/hip_bf16.h>

#define NN 8192
#define KK 256
#define HN 4096
#define TS 128  // square tile
#define BK 64
#define NBLK 2080  // lower-tri incl. diagonal: 64*65/2 = 8*260

typedef __attribute__((ext_vector_type(8))) short bf16x8;
typedef __attribute__((ext_vector_type(4))) float f32x4;

__device__ __forceinline__ void gload_lds16(const void* g, void* l) {
  __builtin_amdgcn_global_load_lds(
      (const __attribute__((address_space(1))) unsigned int*)g,
      (__attribute__((address_space(3))) unsigned int*)l, 16, 0, 0);
}

// ---- Kernel 1: row-normalize z (f32) -> zn (bf16); block 0 zeroes out ----
__global__ void nrm_kernel(const float* __restrict__ z,
                           unsigned short* __restrict__ zn,
                           float* __restrict__ out) {
  if (blockIdx.x == 0 && threadIdx.x == 0) out[0] = 0.0f;
  int row = (blockIdx.x << 2) + (threadIdx.x >> 6);
  int lane = threadIdx.x & 63;
  float4 v = ((const float4*)(z + (size_t)row * KK))[lane];
  float ss = v.x * v.x + v.y * v.y + v.z * v.z + v.w * v.w;
#pragma unroll
  for (int off = 32; off; off >>= 1) ss += __shfl_xor(ss, off, 64);
  float scale = 1.0f / fmaxf(sqrtf(ss), 1e-8f);
  union {
    __hip_bfloat16 h[4];
    ushort4 u;
  } cv;
  cv.h[0] = __float2bfloat16(v.x * scale);
  cv.h[1] = __float2bfloat16(v.y * scale);
  cv.h[2] = __float2bfloat16(v.z * scale);
  cv.h[3] = __float2bfloat16(v.w * scale);
  ((ushort4*)zn)[(size_t)row * 64 + lane] = cv.u;
}

// ---- Kernel 2: symmetric Gram-GEMM, 128x128 lower-triangle tiles ----
// T3 2-phase: double-buffered LDS, STAGE(next) issued BEFORE compute(cur),
// one vmcnt(0)+barrier per K-step after compute. 2 blocks/CU (64 KB LDS).
// p = exp(10*s_ij-10) for j<i; per-wave-private partial slots, no atomics.
__global__ __launch_bounds__(256, 2) void gemm_kernel(
    const unsigned short* __restrict__ zn, float* __restrict__ rowpartT,
    float* __restrict__ colpartT, float* __restrict__ pos) {
  __shared__ short As[2][TS * BK];  // 2 x 16 KiB, XOR-swizzled 16B groups
  __shared__ short Bs[2][TS * BK];  // 2 x 16 KiB

  const int t = threadIdx.x;
  // XCD-aware bijective swizzle (2080 = 8*260), then triangular decode
  int id = ((int)blockIdx.x & 7) * 260 + ((int)blockIdx.x >> 3);
  int s = (int)((sqrtf((float)(8 * id + 1)) - 1.0f) * 0.5f);
  while (s * (s + 1) / 2 > id) --s;
  while ((s + 1) * (s + 2) / 2 <= id) ++s;
  const int bn = id - s * (s + 1) / 2;  // 0..s (bn==s is the diagonal tile)

  const int l = t & 63;
  const int w = t >> 6;   // 0..3
  const int wr = w >> 1;  // 0..1 : 64-row half
  const int wc = w & 1;   // 0..1 : 64-col half

  f32x4 acc[4][4];
  const f32x4 vzero = {0.f, 0.f, 0.f, 0.f};
#pragma unroll
  for (int mi = 0; mi < 4; ++mi)
#pragma unroll
    for (int ni = 0; ni < 4; ++ni) acc[mi][ni] = vzero;

  const char* zb = (const char*)zn;
  const int rloc = t >> 3;                // 0..31
  const int gsrc = (t & 7) ^ (rloc & 7);  // pre-swizzled source 16B-group
  // hoisted per-thread global bases (kt advances by +128 B)
  const char* aG = zb + (size_t)(s * TS + rloc) * 512 + gsrc * 16;
  const char* bG = zb + (size_t)(bn * TS + rloc) * 512 + gsrc * 16;

#define STAGE(buf, kt)                                                    \
  do {                                                                    \
    _Pragma("unroll") for (int ro = 0; ro < 4; ++ro) {                    \
      gload_lds16(aG + (size_t)ro * (32 * 512) + (kt)*128,                \
                  (char*)(&As[buf][0]) + ro * 4096 + t * 16);             \
      gload_lds16(bG + (size_t)ro * (32 * 512) + (kt)*128,                \
                  (char*)(&Bs[buf][0]) + ro * 4096 + t * 16);             \
    }                                                                     \
  } while (0)

  STAGE(0, 0);
  asm volatile("s_waitcnt vmcnt(0)" ::: "memory");
  __syncthreads();

#pragma unroll
  for (int kt = 0; kt < KK / BK; ++kt) {
    const int cur = kt & 1;
    if (kt < KK / BK - 1) STAGE(cur ^ 1, kt + 1);  // prefetch under compute
#pragma unroll
    for (int kk = 0; kk < 2; ++kk) {
      bf16x8 af[4], bfr[4];
      int g = kk * 4 + (l >> 4);
#pragma unroll
      for (int mi = 0; mi < 4; ++mi) {
        int r = wr * 64 + mi * 16 + (l & 15);
        af[mi] = *(const bf16x8*)(&As[cur][0] + r * 64 + ((g ^ (r & 7)) << 3));
      }
#pragma unroll
      for (int ni = 0; ni < 4; ++ni) {
        int r = wc * 64 + ni * 16 + (l & 15);
        bfr[ni] = *(const bf16x8*)(&Bs[cur][0] + r * 64 + ((g ^ (r & 7)) << 3));
      }
#pragma unroll
      for (int mi = 0; mi < 4; ++mi)
#pragma unroll
        for (int ni = 0; ni < 4; ++ni)
          acc[mi][ni] = __builtin_amdgcn_mfma_f32_16x16x32_bf16(
              af[mi], bfr[ni], acc[mi][ni], 0, 0, 0);
    }
    if (kt < KK / BK - 1) {
      asm volatile("s_waitcnt vmcnt(0)" ::: "memory");
      __syncthreads();
    }
  }

  // ---- epilogue: p = exp(10s-10) for gc<gr only; private partial slots ----
  const int g16 = l >> 4;
  const int rowBase = s * TS + wr * 64 + (g16 << 2);
  const int colBase = bn * TS + wc * 64 + (l & 15);
  const float C1 = 14.4269504088896340736f;  // 10*log2(e)
  float rs[4][4];
  float cs[4] = {0.f, 0.f, 0.f, 0.f};
#pragma unroll
  for (int mi = 0; mi < 4; ++mi) {
#pragma unroll
    for (int j = 0; j < 4; ++j) rs[mi][j] = 0.f;
#pragma unroll
    for (int ni = 0; ni < 4; ++ni) {
#pragma unroll
      for (int j = 0; j < 4; ++j) {
        int gr = rowBase + mi * 16 + j;
        int gc = colBase + ni * 16;
        float a = acc[mi][ni][j];
        if (gc == (gr ^ HN)) {  // strictly-lower hit: write both directions
          pos[gr] = a * 10.0f;
          pos[gc] = a * 10.0f;
        }
        float p = (gc < gr) ? exp2f(fmaf(a, C1, -C1)) : 0.0f;
        rs[mi][j] += p;
        cs[ni] += p;
      }
    }
  }
#pragma unroll
  for (int mi = 0; mi < 4; ++mi)
#pragma unroll
    for (int j = 0; j < 4; ++j) {
      float v = rs[mi][j];
      v += __shfl_xor(v, 1, 64);
      v += __shfl_xor(v, 2, 64);
      v += __shfl_xor(v, 4, 64);
      v += __shfl_xor(v, 8, 64);
      rs[mi][j] = v;  // valid in lanes with (l&15)==0
    }
#pragma unroll
  for (int ni = 0; ni < 4; ++ni) {
    float v = cs[ni];
    v += __shfl_xor(v, 16, 64);
    v += __shfl_xor(v, 32, 64);
    cs[ni] = v;  // valid in lanes l<16
  }
  // private-slot stores: one writer per slot element, no merge needed
  if ((l & 15) == 0) {
    float* dst = rowpartT + (size_t)(2 * bn + wc) * NN;
#pragma unroll
    for (int mi = 0; mi < 4; ++mi) {
      float4 v4 = make_float4(rs[mi][0], rs[mi][1], rs[mi][2], rs[mi][3]);
      *(float4*)(dst + rowBase + mi * 16) = v4;
    }
  }
  if (l < 16) {
    float* dst = colpartT + (size_t)(2 * s + wr) * NN;
#pragma unroll
    for (int ni = 0; ni < 4; ++ni) dst[colBase + ni * 16] = cs[ni];
  }
}

// ---- Kernel 3: loss = mean(10 + ln(rowsum_i) - pos_i) ----
__global__ void finalize_kernel(const float* __restrict__ rowpartT,
                                const float* __restrict__ colpartT,
                                const float* __restrict__ pos,
                                float* __restrict__ out) {
  int i = blockIdx.x * 256 + threadIdx.x;  // one row per thread
  int si = i >> 7;
  float sum = 0.f;
  // row slots: 2bn+wc for bn<=si -> k in [0, 2si+2)
  for (int k = 0; k < 2 * si + 2; ++k) sum += rowpartT[(size_t)k * NN + i];
  // col slots: 2s+wr for s>=si -> k in [2si, 128)
  for (int k = 2 * si; k < 128; ++k) sum += colpartT[(size_t)k * NN + i];
  float acc = 10.0f + logf(sum) - pos[i];
#pragma unroll
  for (int off = 32; off; off >>= 1) acc += __shfl_xor(acc, off, 64);
  __shared__ float ws[4];
  if ((threadIdx.x & 63) == 0) ws[threadIdx.x >> 6] = acc;
  __syncthreads();
  if (threadIdx.x == 0)
    atomicAdd(out, (ws[0] + ws[1] + ws[2] + ws[3]) * (1.0f / (float)NN));
}

extern "C" void kernel_launch(void* const* d_in, const int* in_sizes, int n_in,
                              void* d_out, int out_size, void* d_ws,
                              size_t ws_size, hipStream_t stream) {
  const float* z = (const float*)d_in[0];
  float* out = (float*)d_out;
  char* ws = (char*)d_ws;
  unsigned short* zn = (unsigned short*)ws;    // 4 MiB bf16
  float* rowpartT = (float*)(ws + (4 << 20));  // 4 MiB [128][8192]
  float* colpartT = (float*)(ws + (8 << 20));  // 4 MiB [128][8192]
  float* pos = (float*)(ws + (12 << 20));      // 32 KiB

  nrm_kernel<<<NN / 4, 256, 0, stream>>>(z, zn, out);
  gemm_kernel<<<NBLK, 256, 0, stream>>>(zn, rowpartT, colpartT, pos);
  finalize_kernel<<<NN / 256, 256, 0, stream>>>(rowpartT, colpartT, pos, out);
}

// Round 8
// 62.749 us; speedup vs baseline: 1.7645x; 1.2955x over previous
//
#include <hip/hip_runtime.h>
#include <hip/hip_bf16.h>

#define NN 8192
#define KK 256
#define HN 4096
#define TS 128  // square tile
#define BK 64
#define TPB 2      // tiles per block
#define NBLK 1040  // 2080 lower-tri tiles / TPB; 1040 = 8*130

typedef __attribute__((ext_vector_type(8))) short bf16x8;
typedef __attribute__((ext_vector_type(4))) float f32x4;

__device__ __forceinline__ void gload_lds16(const void* g, void* l) {
  __builtin_amdgcn_global_load_lds(
      (const __attribute__((address_space(1))) unsigned int*)g,
      (__attribute__((address_space(3))) unsigned int*)l, 16, 0, 0);
}

__device__ __forceinline__ void decode_tile(int id, int& s, int& bn) {
  int v = (int)((sqrtf((float)(8 * id + 1)) - 1.0f) * 0.5f);
  while (v * (v + 1) / 2 > id) --v;
  while ((v + 1) * (v + 2) / 2 <= id) ++v;
  s = v;
  bn = id - v * (v + 1) / 2;  // 0..s
}

// ---- Kernel 1: row-normalize z (f32) -> zn (bf16); block 0 zeroes out ----
__global__ void nrm_kernel(const float* __restrict__ z,
                           unsigned short* __restrict__ zn,
                           float* __restrict__ out) {
  if (blockIdx.x == 0 && threadIdx.x == 0) out[0] = 0.0f;
  int row = (blockIdx.x << 2) + (threadIdx.x >> 6);
  int lane = threadIdx.x & 63;
  float4 v = ((const float4*)(z + (size_t)row * KK))[lane];
  float ss = v.x * v.x + v.y * v.y + v.z * v.z + v.w * v.w;
#pragma unroll
  for (int off = 32; off; off >>= 1) ss += __shfl_xor(ss, off, 64);
  float scale = 1.0f / fmaxf(sqrtf(ss), 1e-8f);
  union {
    __hip_bfloat16 h[4];
    ushort4 u;
  } cv;
  cv.h[0] = __float2bfloat16(v.x * scale);
  cv.h[1] = __float2bfloat16(v.y * scale);
  cv.h[2] = __float2bfloat16(v.z * scale);
  cv.h[3] = __float2bfloat16(v.w * scale);
  ((ushort4*)zn)[(size_t)row * 64 + lane] = cv.u;
}

// ---- Kernel 2: symmetric Gram-GEMM, 128x128 lower-triangle tiles,
// TPB tiles per block. Flattened step pipeline: STAGE(step+1) issued before
// compute(step); at tile boundaries the next tile's first slice streams in
// under the current tile's epilogue. Per-wave-private partials, no atomics.
__global__ __launch_bounds__(256, 2) void gemm_kernel(
    const unsigned short* __restrict__ zn, float* __restrict__ rowpartT,
    float* __restrict__ colpartT, float* __restrict__ pos) {
  __shared__ short As[2][TS * BK];  // 2 x 16 KiB, XOR-swizzled 16B groups
  __shared__ short Bs[2][TS * BK];  // 2 x 16 KiB

  const int t = threadIdx.x;
  // XCD-aware bijective swizzle (1040 = 8*130); TPB consecutive tile ids
  const int tile0 = (((int)blockIdx.x & 7) * 130 + ((int)blockIdx.x >> 3)) * TPB;
  int sA[TPB], bA[TPB];
#pragma unroll
  for (int tt = 0; tt < TPB; ++tt) decode_tile(tile0 + tt, sA[tt], bA[tt]);

  const int l = t & 63;
  const int w = t >> 6;   // 0..3
  const int wr = w >> 1;  // 0..1 : 64-row half
  const int wc = w & 1;   // 0..1 : 64-col half

  const char* zb = (const char*)zn;
  const int rloc = t >> 3;                // 0..31
  const int gsrc = (t & 7) ^ (rloc & 7);  // pre-swizzled source 16B-group

#define STAGE2(t_, kt_)                                                       \
  do {                                                                        \
    const int _buf = (((t_)*4 + (kt_)) & 1);                                  \
    const char* _aG =                                                         \
        zb + (size_t)(sA[t_] * TS + rloc) * 512 + gsrc * 16 + (kt_)*128;      \
    const char* _bG =                                                         \
        zb + (size_t)(bA[t_] * TS + rloc) * 512 + gsrc * 16 + (kt_)*128;      \
    _Pragma("unroll") for (int ro = 0; ro < 4; ++ro) {                        \
      gload_lds16(_aG + (size_t)ro * (32 * 512),                              \
                  (char*)(&As[_buf][0]) + ro * 4096 + t * 16);                \
      gload_lds16(_bG + (size_t)ro * (32 * 512),                              \
                  (char*)(&Bs[_buf][0]) + ro * 4096 + t * 16);                \
    }                                                                         \
  } while (0)

  STAGE2(0, 0);
  asm volatile("s_waitcnt vmcnt(0)" ::: "memory");
  __syncthreads();

  const float C1 = 14.4269504088896340736f;  // 10*log2(e)

#pragma unroll
  for (int tt = 0; tt < TPB; ++tt) {
    f32x4 acc[4][4];
    const f32x4 vzero = {0.f, 0.f, 0.f, 0.f};
#pragma unroll
    for (int mi = 0; mi < 4; ++mi)
#pragma unroll
      for (int ni = 0; ni < 4; ++ni) acc[mi][ni] = vzero;

#pragma unroll
    for (int kt = 0; kt < 4; ++kt) {
      const int step = tt * 4 + kt;
      const int cur = step & 1;
      if (step < TPB * 4 - 1) {  // prefetch next step (crosses tile bounds)
        const int ns = step + 1;
        STAGE2(ns >> 2, ns & 3);
      }
#pragma unroll
      for (int kk = 0; kk < 2; ++kk) {
        bf16x8 af[4], bfr[4];
        int g = kk * 4 + (l >> 4);
#pragma unroll
        for (int mi = 0; mi < 4; ++mi) {
          int r = wr * 64 + mi * 16 + (l & 15);
          af[mi] =
              *(const bf16x8*)(&As[cur][0] + r * 64 + ((g ^ (r & 7)) << 3));
        }
#pragma unroll
        for (int ni = 0; ni < 4; ++ni) {
          int r = wc * 64 + ni * 16 + (l & 15);
          bfr[ni] =
              *(const bf16x8*)(&Bs[cur][0] + r * 64 + ((g ^ (r & 7)) << 3));
        }
        __builtin_amdgcn_s_setprio(1);
#pragma unroll
        for (int mi = 0; mi < 4; ++mi)
#pragma unroll
          for (int ni = 0; ni < 4; ++ni)
            acc[mi][ni] = __builtin_amdgcn_mfma_f32_16x16x32_bf16(
                af[mi], bfr[ni], acc[mi][ni], 0, 0, 0);
        __builtin_amdgcn_s_setprio(0);
      }
      if (kt < 3) {
        asm volatile("s_waitcnt vmcnt(0)" ::: "memory");
        __syncthreads();
      }
    }

    // ---- epilogue (no LDS): overlaps the next tile's in-flight stage ----
    const int g16 = l >> 4;
    const int rowBase = sA[tt] * TS + wr * 64 + (g16 << 2);
    const int colBase = bA[tt] * TS + wc * 64 + (l & 15);
    float rs[4][4];
    float cs[4] = {0.f, 0.f, 0.f, 0.f};
#pragma unroll
    for (int mi = 0; mi < 4; ++mi) {
#pragma unroll
      for (int j = 0; j < 4; ++j) rs[mi][j] = 0.f;
#pragma unroll
      for (int ni = 0; ni < 4; ++ni) {
#pragma unroll
        for (int j = 0; j < 4; ++j) {
          int gr = rowBase + mi * 16 + j;
          int gc = colBase + ni * 16;
          float a = acc[mi][ni][j];
          if (gc == (gr ^ HN)) {  // strictly-lower hit: both directions
            pos[gr] = a * 10.0f;
            pos[gc] = a * 10.0f;
          }
          float p = (gc < gr) ? exp2f(fmaf(a, C1, -C1)) : 0.0f;
          rs[mi][j] += p;
          cs[ni] += p;
        }
      }
    }
#pragma unroll
    for (int mi = 0; mi < 4; ++mi)
#pragma unroll
      for (int j = 0; j < 4; ++j) {
        float v = rs[mi][j];
        v += __shfl_xor(v, 1, 64);
        v += __shfl_xor(v, 2, 64);
        v += __shfl_xor(v, 4, 64);
        v += __shfl_xor(v, 8, 64);
        rs[mi][j] = v;  // valid in lanes with (l&15)==0
      }
#pragma unroll
    for (int ni = 0; ni < 4; ++ni) {
      float v = cs[ni];
      v += __shfl_xor(v, 16, 64);
      v += __shfl_xor(v, 32, 64);
      cs[ni] = v;  // valid in lanes l<16
    }
    if ((l & 15) == 0) {
      float* dst = rowpartT + (size_t)(2 * bA[tt] + wc) * NN;
#pragma unroll
      for (int mi = 0; mi < 4; ++mi) {
        float4 v4 = make_float4(rs[mi][0], rs[mi][1], rs[mi][2], rs[mi][3]);
        *(float4*)(dst + rowBase + mi * 16) = v4;
      }
    }
    if (l < 16) {
      float* dst = colpartT + (size_t)(2 * sA[tt] + wr) * NN;
#pragma unroll
      for (int ni = 0; ni < 4; ++ni) dst[colBase + ni * 16] = cs[ni];
    }
    if (tt < TPB - 1) {
      asm volatile("s_waitcnt vmcnt(0)" ::: "memory");
      __syncthreads();
    }
  }
}

// ---- Kernel 3: loss = mean(10 + ln(rowsum_i) - pos_i) ----
__global__ void finalize_kernel(const float* __restrict__ rowpartT,
                                const float* __restrict__ colpartT,
                                const float* __restrict__ pos,
                                float* __restrict__ out) {
  int i = blockIdx.x * 256 + threadIdx.x;  // one row per thread
  int si = i >> 7;
  float sum = 0.f;
  // row slots: 2bn+wc for bn<=si -> k in [0, 2si+2)
#pragma unroll 4
  for (int k = 0; k < 2 * si + 2; ++k) sum += rowpartT[(size_t)k * NN + i];
  // col slots: 2s+wr for s>=si -> k in [2si, 128)
#pragma unroll 4
  for (int k = 2 * si; k < 128; ++k) sum += colpartT[(size_t)k * NN + i];
  float acc = 10.0f + logf(sum) - pos[i];
#pragma unroll
  for (int off = 32; off; off >>= 1) acc += __shfl_xor(acc, off, 64);
  __shared__ float ws[4];
  if ((threadIdx.x & 63) == 0) ws[threadIdx.x >> 6] = acc;
  __syncthreads();
  if (threadIdx.x == 0)
    atomicAdd(out, (ws[0] + ws[1] + ws[2] + ws[3]) * (1.0f / (float)NN));
}

extern "C" void kernel_launch(void* const* d_in, const int* in_sizes, int n_in,
                              void* d_out, int out_size, void* d_ws,
                              size_t ws_size, hipStream_t stream) {
  const float* z = (const float*)d_in[0];
  float* out = (float*)d_out;
  char* ws = (char*)d_ws;
  unsigned short* zn = (unsigned short*)ws;    // 4 MiB bf16
  float* rowpartT = (float*)(ws + (4 << 20));  // 4 MiB [128][8192]
  float* colpartT = (float*)(ws + (8 << 20));  // 4 MiB [128][8192]
  float* pos = (float*)(ws + (12 << 20));      // 32 KiB

  nrm_kernel<<<NN / 4, 256, 0, stream>>>(z, zn, out);
  gemm_kernel<<<NBLK, 256, 0, stream>>>(zn, rowpartT, colpartT, pos);
  finalize_kernel<<<NN / 256, 256, 0, stream>>>(rowpartT, colpartT, pos, out);
}